// Round 6
// baseline (702.948 us; speedup 1.0000x reference)
//
#include <hip/hip_runtime.h>

// 2-layer GRU (T=1000 serial, B=512) + FC + log_softmax.
// Pass 1: ax[b,t] = x_t @ W1x + b1 (both gates) -> d_ws, per-lane (z,g) float2.
// Pass 2: 256 waves, each interleaving TWO batch elements, skewed layer
//         mapping (lanes 0..31 = GRU1 units @ t, lanes 32..51 = GRU2 @ t-1).
//         h broadcast via immediate-encoded ds_swizzle (BitMode or_mask=k):
//         no readlane (SGPR hazards), no bpermute (address VGPR movs).
//         Upper half gets h1 via one __shfl_xor(h,32) mirror + cndmask.
//         Ping-pong: swzA -> dotB -> swzB -> dotA, so each element's swizzle
//         batch latency is covered by the partner's packed-FMA dot.

typedef float v2f __attribute__((ext_vector_type(2)));

constexpr int FBINS  = 40;
constexpr int L1     = 32;
constexpr int L2     = 20;
constexpr int L3     = 16;
constexpr int NCLASS = 10;
constexpr int T      = 1000;
constexpr int KTOT   = L1 + L2;   // 52
constexpr float LOG2E = 1.4426950408889634f;
constexpr float LN2   = 0.6931471805599453f;

__device__ __forceinline__ float rl(float v, int l) {
    return __uint_as_float(__builtin_amdgcn_readlane(__float_as_uint(v), l));
}

// ds_swizzle BitMode broadcast: every lane reads group-lane K of its 32-half.
template<int K>
__device__ __forceinline__ float swz(float v) {
    return __uint_as_float((unsigned)__builtin_amdgcn_ds_swizzle(
        (int)__float_as_uint(v), (K << 5)));
}
template<int K, int END, int DST>
struct SwzLoop {
    static __device__ __forceinline__ void run(float src, v2f* sh) {
        sh[DST + K / 2].x = swz<K>(src);
        sh[DST + K / 2].y = swz<K + 1>(src);
        SwzLoop<K + 2, END, DST>::run(src, sh);
    }
};
template<int END, int DST>
struct SwzLoop<END, END, DST> {
    static __device__ __forceinline__ void run(float, v2f*) {}
};

// ---------------- pass 1: x-projection ----------------
constexpr int TCH = 100;
__global__ __launch_bounds__(256) void xproj_kernel(
    const float* __restrict__ xg,
    const float* __restrict__ wz1, const float* __restrict__ bz1,
    const float* __restrict__ wh1, const float* __restrict__ bh1,
    float* __restrict__ ax, int t0, int tcnt, int segcap)
{
    __shared__ float xs[TCH * FBINS];
    const int tid = threadIdx.x, lane = tid & 63;
    const int b   = blockIdx.x;
    const int lt0 = blockIdx.y * TCH;
    const int cnt = min(TCH, tcnt - lt0);
    const float* src = xg + ((size_t)b * T + t0 + lt0) * FBINS;
    const int ndw = cnt * FBINS;
    for (int i = tid; i < ndw; i += 256) xs[i] = src[i];
    __syncthreads();

    const int j = lane & 31;
    const float* wp = (lane < 32) ? wz1 : wh1;
    float w[FBINS];
    #pragma unroll
    for (int k = 0; k < FBINS; ++k) w[k] = wp[k * L1 + j];
    const float bias = (lane < 32) ? bz1[j] : bh1[j];
    const int slot = j * 2 + (lane >> 5);

    const int wv = tid >> 6;
    for (int lt = wv; lt < cnt; lt += 4) {
        const float* xp = xs + lt * FBINS;
        float a0 = bias, a1 = 0.f, a2 = 0.f, a3 = 0.f;
        #pragma unroll
        for (int k = 0; k < FBINS; k += 4) {
            a0 = fmaf(xp[k+0], w[k+0], a0);
            a1 = fmaf(xp[k+1], w[k+1], a1);
            a2 = fmaf(xp[k+2], w[k+2], a2);
            a3 = fmaf(xp[k+3], w[k+3], a3);
        }
        ax[((size_t)b * segcap + lt0 + lt) * 64 + slot] = (a0 + a1) + (a2 + a3);
    }
}

// ---------------- pass 2: interleaved recurrence ----------------
constexpr int GS = 4;
__global__ __launch_bounds__(64, 1) void rec_kernel(
    const float* __restrict__ ax,
    const float* __restrict__ wz1, const float* __restrict__ wh1,
    const float* __restrict__ wz2, const float* __restrict__ bz2,
    const float* __restrict__ wh2, const float* __restrict__ bh2,
    const float* __restrict__ w3,  const float* __restrict__ b3,
    const float* __restrict__ w4,  const float* __restrict__ b4,
    float* __restrict__ hws, float* __restrict__ outg,
    int tcnt, int segcap, int first, int last, int Bsz)
{
    const int lane = threadIdx.x;
    const int j    = lane & 31;
    const bool lo  = lane < 32;
    const int j2   = (j < L2) ? j : 0;

    const int e0 = blockIdx.x * 2;
    int e1 = e0 + 1; if (e1 >= Bsz) e1 = e0;
    const bool dup = (e1 == e0);

    // shared per-lane weight columns (v2f pairs, aligned with sh pairs)
    v2f wZ[KTOT / 2], wG[KTOT / 2];
    #pragma unroll
    for (int k = 0; k < L1; k += 2) {
        wZ[k/2].x = lo ? wz1[(FBINS + k)     * L1 + j] : wz2[k       * L2 + j2];
        wZ[k/2].y = lo ? wz1[(FBINS + k + 1) * L1 + j] : wz2[(k + 1) * L2 + j2];
        wG[k/2].x = lo ? wh1[(FBINS + k)     * L1 + j] : wh2[k       * L2 + j2];
        wG[k/2].y = lo ? wh1[(FBINS + k + 1) * L1 + j] : wh2[(k + 1) * L2 + j2];
    }
    #pragma unroll
    for (int k = 0; k < L2; k += 2) {
        wZ[(L1+k)/2].x = lo ? 0.f : wz2[(L1 + k)     * L2 + j2];
        wZ[(L1+k)/2].y = lo ? 0.f : wz2[(L1 + k + 1) * L2 + j2];
        wG[(L1+k)/2].x = lo ? 0.f : wh2[(L1 + k)     * L2 + j2];
        wG[(L1+k)/2].y = lo ? 0.f : wh2[(L1 + k + 1) * L2 + j2];
    }
    const float initZ = lo ? 0.f : bz2[j2];
    const float initG = lo ? 0.f : bh2[j2];

    const float up0 = first ? 0.f : hws[e0 * 64 + 32 + j2];
    const float up1 = first ? 0.f : hws[e1 * 64 + 32 + j2];
    float hA = lo ? (first ? 0.f : hws[e0 * 64 + j]) : up0;
    float hB = lo ? (first ? 0.f : hws[e1 * 64 + j]) : up1;

    const float2* ap0 = (const float2*)ax + (size_t)e0 * segcap * 32 + j;
    const float2* ap1 = (const float2*)ax + (size_t)e1 * segcap * 32 + j;

    // broadcast batch: sh[0..15] = h1 pairs (needs cross-half mirror for the
    // upper half), sh[16..25] = h2 pairs (half-local swizzle of h directly;
    // lower half gets garbage there, multiplied by zero weights).
    auto swz_all = [&](float h, v2f* sh) {
        float mir = __shfl_xor(h, 32);              // issue early (DS)
        SwzLoop<0, L2, L1 / 2>::run(h, sh);         // h2 part, no mir dep
        float hsrc1 = lo ? h : mir;                 // h1 in both halves
        SwzLoop<0, L1, 0>::run(hsrc1, sh);          // h1 part
    };

    auto dot = [&](const v2f (&sh)[KTOT / 2], float2 axv) -> float2 {
        v2f za = {lo ? axv.x : initZ, 0.f}, zb = {0.f, 0.f};
        v2f ga = {lo ? axv.y : initG, 0.f}, gb = {0.f, 0.f};
        #pragma unroll
        for (int c = 0; c < KTOT / 2; c += 2) {
            za = __builtin_elementwise_fma(sh[c],     wZ[c],     za);
            zb = __builtin_elementwise_fma(sh[c + 1], wZ[c + 1], zb);
            ga = __builtin_elementwise_fma(sh[c],     wG[c],     ga);
            gb = __builtin_elementwise_fma(sh[c + 1], wG[c + 1], gb);
        }
        v2f zs = za + zb, gs = ga + gb;
        return make_float2(zs.x + zs.y, gs.x + gs.y);
    };

    auto act = [&](float z, float g, float h) {
        float ez = __builtin_amdgcn_exp2f(-z * LOG2E);        // sigmoid(z)
        float s  = __builtin_amdgcn_rcpf(1.f + ez);
        float eg = __builtin_amdgcn_exp2f(-2.f * g * LOG2E);  // tanh(g)
        float r  = __builtin_amdgcn_rcpf(1.f + eg);
        float gt = fmaf(2.f, r, -1.f);
        return fmaf(s, gt - h, h);                            // (1-z)h + z*g
    };

    v2f shB[KTOT / 2];
    swz_all(hB, shB);                 // prologue: shB for round 0's dotB

    // ping-pong round: swzA -> dotB -> swzB -> dotA.
    // Each swizzle batch's latency is covered by the partner's dot+act.
    auto roundfn = [&](float2 axA, float2 axB, bool fix) {
        v2f shA[KTOT / 2];
        swz_all(hA, shA);
        {
            float2 zg = dot(shB, axB);
            hB = act(zg.x, zg.y, hB);
            if (fix) hB = lo ? hB : up1;     // discard junk first GRU2 step
        }
        swz_all(hB, shB);                    // for NEXT round's dotB
        {
            float2 zg = dot(shA, axA);
            hA = act(zg.x, zg.y, hA);
            if (fix) hA = lo ? hA : up0;
        }
    };

    // ---- pipelined loop, GS-step groups, double-buffered register prefetch
    float2 a0A[GS], a0B[GS], a1A[GS], a1B[GS];
    const int ng = tcnt / GS;                    // tcnt multiple of 8 -> even
    #pragma unroll
    for (int i = 0; i < GS; ++i) { a0A[i] = ap0[(size_t)i * 32];        a1A[i] = ap1[(size_t)i * 32]; }
    #pragma unroll
    for (int i = 0; i < GS; ++i) { a0B[i] = ap0[(size_t)(GS + i) * 32]; a1B[i] = ap1[(size_t)(GS + i) * 32]; }

    roundfn(a0A[0], a1A[0], true);               // round 0 with skew fixup
    #pragma unroll
    for (int i = 1; i < GS; ++i) roundfn(a0A[i], a1A[i], false);
    if (2 < ng) {
        #pragma unroll
        for (int i = 0; i < GS; ++i) { a0A[i] = ap0[(size_t)(2*GS+i)*32]; a1A[i] = ap1[(size_t)(2*GS+i)*32]; }
    }

    #pragma unroll 1
    for (int gp = 1; gp < ng; gp += 2) {
        #pragma unroll
        for (int i = 0; i < GS; ++i) roundfn(a0B[i], a1B[i], false);
        if (gp + 2 < ng) {
            #pragma unroll
            for (int i = 0; i < GS; ++i) { a0B[i] = ap0[(size_t)((gp+2)*GS+i)*32]; a1B[i] = ap1[(size_t)((gp+2)*GS+i)*32]; }
        }
        if (gp + 1 < ng) {
            #pragma unroll
            for (int i = 0; i < GS; ++i) roundfn(a0A[i], a1A[i], false);
            if (gp + 3 < ng) {
                #pragma unroll
                for (int i = 0; i < GS; ++i) { a0A[i] = ap0[(size_t)((gp+3)*GS+i)*32]; a1A[i] = ap1[(size_t)((gp+3)*GS+i)*32]; }
            }
        }
    }

    // save h1 (lower) before the epilogue junks it, then finish last GRU2 step
    if (!last && lo) {
        hws[e0 * 64 + j] = hA;
        if (!dup) hws[e1 * 64 + j] = hB;
    }
    roundfn(make_float2(0.f, 0.f), make_float2(0.f, 0.f), false);
    if (!last) {
        if (!lo && j < L2) {
            hws[e0 * 64 + 32 + j] = hA;
            if (!dup) hws[e1 * 64 + 32 + j] = hB;
        }
        return;
    }

    // ---- tail: FC3+ReLU, FC4, log_softmax (per element; h2 = upper lanes)
    auto tail = [&](float hfin, float* op) {
        float s2[L2];
        #pragma unroll
        for (int k = 0; k < L2; ++k) s2[k] = rl(hfin, 32 + k);
        float a3 = 0.f;
        if (lane < L3) {
            a3 = b3[lane];
            #pragma unroll
            for (int k = 0; k < L2; ++k) a3 = fmaf(s2[k], w3[k * L3 + lane], a3);
            a3 = fmaxf(a3, 0.f);
        }
        float s3[L3];
        #pragma unroll
        for (int k = 0; k < L3; ++k) s3[k] = rl(a3, k);
        float a4 = 0.f;
        if (lane < NCLASS) {
            a4 = b4[lane];
            #pragma unroll
            for (int k = 0; k < L3; ++k) a4 = fmaf(s3[k], w4[k * NCLASS + lane], a4);
        }
        float s4[NCLASS];
        #pragma unroll
        for (int k = 0; k < NCLASS; ++k) s4[k] = rl(a4, k);
        float m = s4[0];
        #pragma unroll
        for (int k = 1; k < NCLASS; ++k) m = fmaxf(m, s4[k]);
        float ss = 0.f;
        #pragma unroll
        for (int k = 0; k < NCLASS; ++k)
            ss += __builtin_amdgcn_exp2f((s4[k] - m) * LOG2E);
        float lse = m + __builtin_amdgcn_logf(ss) * LN2;
        if (lane < NCLASS) op[lane] = s4[lane] - lse;
    };
    tail(hA, outg + e0 * NCLASS);
    tail(hB, outg + e1 * NCLASS);
}

extern "C" void kernel_launch(void* const* d_in, const int* in_sizes, int n_in,
                              void* d_out, int out_size, void* d_ws, size_t ws_size,
                              hipStream_t stream) {
    const float* x   = (const float*)d_in[0];
    const float* wz1 = (const float*)d_in[1];
    const float* bz1 = (const float*)d_in[2];
    const float* wh1 = (const float*)d_in[3];
    const float* bh1 = (const float*)d_in[4];
    const float* wz2 = (const float*)d_in[5];
    const float* bz2 = (const float*)d_in[6];
    const float* wh2 = (const float*)d_in[7];
    const float* bh2 = (const float*)d_in[8];
    const float* w3  = (const float*)d_in[9];
    const float* b3  = (const float*)d_in[10];
    const float* w4  = (const float*)d_in[11];
    const float* b4  = (const float*)d_in[12];
    float* out = (float*)d_out;

    const int Bsz = in_sizes[0] / (T * FBINS);          // 512

    float* hws = (float*)d_ws;
    float* axw = hws + (size_t)Bsz * 64;
    const size_t hbytes = (size_t)Bsz * 64 * sizeof(float);
    const size_t per_t  = (size_t)Bsz * 64 * sizeof(float);

    int segT = T;
    if (ws_size < hbytes + (size_t)T * per_t) {
        size_t avail = (ws_size > hbytes) ? ws_size - hbytes : 0;
        size_t s = avail / per_t;
        segT = (s > (size_t)T) ? T : (int)s;
        segT &= ~7;
        if (segT < 8) segT = 8;
    }

    const int nblk = (Bsz + 1) / 2;
    for (int t0 = 0; t0 < T; t0 += segT) {
        const int tc = (T - t0 < segT) ? (T - t0) : segT;
        dim3 g1(Bsz, (tc + TCH - 1) / TCH);
        xproj_kernel<<<g1, dim3(256), 0, stream>>>(x, wz1, bz1, wh1, bh1,
                                                   axw, t0, tc, segT);
        rec_kernel<<<dim3(nblk), dim3(64), 0, stream>>>(axw,
            wz1, wh1, wz2, bz2, wh2, bh2, w3, b3, w4, b4,
            hws, out, tc, segT, t0 == 0 ? 1 : 0, (t0 + tc >= T) ? 1 : 0, Bsz);
    }
}

// Round 7
// 497.120 us; speedup vs baseline: 1.4140x; 1.4140x over previous
//
#include <hip/hip_runtime.h>

// 2-layer GRU (T=1000 serial, B=512) + FC + log_softmax.
// Pass 1: ax[b,t] = x_t @ W1x + b1 (both gates) -> d_ws, per-lane (z,g) float2.
// Pass 2: 256 waves, each interleaving TWO batch elements, skewed layer
//         mapping (lanes 0..31 = GRU1 units @ t, lanes 32..51 = GRU2 @ t-1).
//         h broadcast via LDS transpose: 1 ds_write_b32 + 13 uniform
//         ds_read_b128 per element-step (4 values per DS op), software-
//         pipelined across the A/B ping-pong so each element's LDS round-trip
//         latency is covered by the partner's packed-FMA dot. DS ops of one
//         wave execute in order, so write->read same address needs no fence;
//         lgkmcnt only gates register use, which the schedule naturally delays.

typedef float v2f __attribute__((ext_vector_type(2)));
typedef float v4f __attribute__((ext_vector_type(4)));

constexpr int FBINS  = 40;
constexpr int L1     = 32;
constexpr int L2     = 20;
constexpr int L3     = 16;
constexpr int NCLASS = 10;
constexpr int T      = 1000;
constexpr int KTOT   = L1 + L2;   // 52
constexpr int NQUAD  = KTOT / 4;  // 13
constexpr float LOG2E = 1.4426950408889634f;
constexpr float LN2   = 0.6931471805599453f;

__device__ __forceinline__ float rl(float v, int l) {
    return __uint_as_float(__builtin_amdgcn_readlane(__float_as_uint(v), l));
}

// ---------------- pass 1: x-projection ----------------
constexpr int TCH = 100;
__global__ __launch_bounds__(256) void xproj_kernel(
    const float* __restrict__ xg,
    const float* __restrict__ wz1, const float* __restrict__ bz1,
    const float* __restrict__ wh1, const float* __restrict__ bh1,
    float* __restrict__ ax, int t0, int tcnt, int segcap)
{
    __shared__ float xs[TCH * FBINS];
    const int tid = threadIdx.x, lane = tid & 63;
    const int b   = blockIdx.x;
    const int lt0 = blockIdx.y * TCH;
    const int cnt = min(TCH, tcnt - lt0);
    const float* src = xg + ((size_t)b * T + t0 + lt0) * FBINS;
    const int ndw = cnt * FBINS;
    for (int i = tid; i < ndw; i += 256) xs[i] = src[i];
    __syncthreads();

    const int j = lane & 31;
    const float* wp = (lane < 32) ? wz1 : wh1;
    float w[FBINS];
    #pragma unroll
    for (int k = 0; k < FBINS; ++k) w[k] = wp[k * L1 + j];
    const float bias = (lane < 32) ? bz1[j] : bh1[j];
    const int slot = j * 2 + (lane >> 5);

    const int wv = tid >> 6;
    for (int lt = wv; lt < cnt; lt += 4) {
        const float* xp = xs + lt * FBINS;
        float a0 = bias, a1 = 0.f, a2 = 0.f, a3 = 0.f;
        #pragma unroll
        for (int k = 0; k < FBINS; k += 4) {
            a0 = fmaf(xp[k+0], w[k+0], a0);
            a1 = fmaf(xp[k+1], w[k+1], a1);
            a2 = fmaf(xp[k+2], w[k+2], a2);
            a3 = fmaf(xp[k+3], w[k+3], a3);
        }
        ax[((size_t)b * segcap + lt0 + lt) * 64 + slot] = (a0 + a1) + (a2 + a3);
    }
}

// ---------------- pass 2: interleaved recurrence ----------------
constexpr int GS = 4;
__global__ __launch_bounds__(64, 1) void rec_kernel(
    const float* __restrict__ ax,
    const float* __restrict__ wz1, const float* __restrict__ wh1,
    const float* __restrict__ wz2, const float* __restrict__ bz2,
    const float* __restrict__ wh2, const float* __restrict__ bh2,
    const float* __restrict__ w3,  const float* __restrict__ b3,
    const float* __restrict__ w4,  const float* __restrict__ b4,
    float* __restrict__ hws, float* __restrict__ outg,
    int tcnt, int segcap, int first, int last, int Bsz)
{
    __shared__ alignas(16) float hlsA[64];
    __shared__ alignas(16) float hlsB[64];

    const int lane = threadIdx.x;
    const int j    = lane & 31;
    const bool lo  = lane < 32;
    const int j2   = (j < L2) ? j : 0;

    const int e0 = blockIdx.x * 2;
    int e1 = e0 + 1; if (e1 >= Bsz) e1 = e0;
    const bool dup = (e1 == e0);

    // per-lane weight columns as v2f pairs over K (even/odd K packed together)
    // lower lanes: GRU1 h-part (K=0..31 valid, 32..51 zero-padded)
    // upper lanes: GRU2 full (K=0..31 -> h1, 32..51 -> h2)
    v2f wZ[KTOT / 2], wG[KTOT / 2];
    #pragma unroll
    for (int k = 0; k < L1; k += 2) {
        wZ[k/2].x = lo ? wz1[(FBINS + k)     * L1 + j] : wz2[k       * L2 + j2];
        wZ[k/2].y = lo ? wz1[(FBINS + k + 1) * L1 + j] : wz2[(k + 1) * L2 + j2];
        wG[k/2].x = lo ? wh1[(FBINS + k)     * L1 + j] : wh2[k       * L2 + j2];
        wG[k/2].y = lo ? wh1[(FBINS + k + 1) * L1 + j] : wh2[(k + 1) * L2 + j2];
    }
    #pragma unroll
    for (int k = 0; k < L2; k += 2) {
        wZ[(L1+k)/2].x = lo ? 0.f : wz2[(L1 + k)     * L2 + j2];
        wZ[(L1+k)/2].y = lo ? 0.f : wz2[(L1 + k + 1) * L2 + j2];
        wG[(L1+k)/2].x = lo ? 0.f : wh2[(L1 + k)     * L2 + j2];
        wG[(L1+k)/2].y = lo ? 0.f : wh2[(L1 + k + 1) * L2 + j2];
    }
    const float initZ = lo ? 0.f : bz2[j2];
    const float initG = lo ? 0.f : bh2[j2];

    const float up0 = first ? 0.f : hws[e0 * 64 + 32 + j2];
    const float up1 = first ? 0.f : hws[e1 * 64 + 32 + j2];
    float hA = lo ? (first ? 0.f : hws[e0 * 64 + j]) : up0;
    float hB = lo ? (first ? 0.f : hws[e1 * 64 + j]) : up1;

    const float2* ap0 = (const float2*)ax + (size_t)e0 * segcap * 32 + j;
    const float2* ap1 = (const float2*)ax + (size_t)e1 * segcap * 32 + j;

    auto dot = [&](const v4f (&sh)[NQUAD], float2 axv) -> float2 {
        v2f z0 = {lo ? axv.x : initZ, 0.f}, z1 = {0.f, 0.f};
        v2f g0 = {lo ? axv.y : initG, 0.f}, g1 = {0.f, 0.f};
        #pragma unroll
        for (int q = 0; q < NQUAD; ++q) {
            v2f a = __builtin_shufflevector(sh[q], sh[q], 0, 1);
            v2f b = __builtin_shufflevector(sh[q], sh[q], 2, 3);
            z0 = __builtin_elementwise_fma(a, wZ[2*q],   z0);
            z1 = __builtin_elementwise_fma(b, wZ[2*q+1], z1);
            g0 = __builtin_elementwise_fma(a, wG[2*q],   g0);
            g1 = __builtin_elementwise_fma(b, wG[2*q+1], g1);
        }
        v2f zs = z0 + z1, gs = g0 + g1;
        return make_float2(zs.x + zs.y, gs.x + gs.y);
    };

    auto act = [&](float z, float g, float h) {
        float ez = __builtin_amdgcn_exp2f(-z * LOG2E);        // sigmoid(z)
        float s  = __builtin_amdgcn_rcpf(1.f + ez);
        float eg = __builtin_amdgcn_exp2f(-2.f * g * LOG2E);  // tanh(g)
        float r  = __builtin_amdgcn_rcpf(1.f + eg);
        float gt = fmaf(2.f, r, -1.f);
        return fmaf(s, gt - h, h);                            // (1-z)h + z*g
    };

    // prologue: seed LDS with h(0); preload shB for round 0's dotB
    hlsA[lane] = hA;
    hlsB[lane] = hB;
    v4f shB[NQUAD];
    #pragma unroll
    for (int q = 0; q < NQUAD; ++q) shB[q] = ((const v4f*)hlsB)[q];

    // one round = one GRU step for each element, pipelined:
    //   readA -> dotB (covers readA) -> writeB,readB -> dotA (covers readB) -> writeA
    auto roundfn = [&](float2 axA, float2 axB, bool fix) {
        v4f shA[NQUAD];
        #pragma unroll
        for (int q = 0; q < NQUAD; ++q) shA[q] = ((const v4f*)hlsA)[q];

        float2 zg = dot(shB, axB);
        hB = act(zg.x, zg.y, hB);
        if (fix) hB = lo ? hB : up1;          // discard junk first GRU2 step
        hlsB[lane] = hB;
        #pragma unroll
        for (int q = 0; q < NQUAD; ++q) shB[q] = ((const v4f*)hlsB)[q];

        zg = dot(shA, axA);
        hA = act(zg.x, zg.y, hA);
        if (fix) hA = lo ? hA : up0;
        hlsA[lane] = hA;
    };

    // ---- pipelined loop, GS-step groups, double-buffered register prefetch
    float2 a0A[GS], a0B[GS], a1A[GS], a1B[GS];
    const int ng = tcnt / GS;                    // tcnt multiple of 8 -> even
    #pragma unroll
    for (int i = 0; i < GS; ++i) { a0A[i] = ap0[(size_t)i * 32];        a1A[i] = ap1[(size_t)i * 32]; }
    #pragma unroll
    for (int i = 0; i < GS; ++i) { a0B[i] = ap0[(size_t)(GS + i) * 32]; a1B[i] = ap1[(size_t)(GS + i) * 32]; }

    roundfn(a0A[0], a1A[0], true);               // round 0 with skew fixup
    #pragma unroll
    for (int i = 1; i < GS; ++i) roundfn(a0A[i], a1A[i], false);
    if (2 < ng) {
        #pragma unroll
        for (int i = 0; i < GS; ++i) { a0A[i] = ap0[(size_t)(2*GS+i)*32]; a1A[i] = ap1[(size_t)(2*GS+i)*32]; }
    }

    #pragma unroll 1
    for (int gp = 1; gp < ng; gp += 2) {
        #pragma unroll
        for (int i = 0; i < GS; ++i) roundfn(a0B[i], a1B[i], false);
        if (gp + 2 < ng) {
            #pragma unroll
            for (int i = 0; i < GS; ++i) { a0B[i] = ap0[(size_t)((gp+2)*GS+i)*32]; a1B[i] = ap1[(size_t)((gp+2)*GS+i)*32]; }
        }
        if (gp + 1 < ng) {
            #pragma unroll
            for (int i = 0; i < GS; ++i) roundfn(a0A[i], a1A[i], false);
            if (gp + 3 < ng) {
                #pragma unroll
                for (int i = 0; i < GS; ++i) { a0A[i] = ap0[(size_t)((gp+3)*GS+i)*32]; a1A[i] = ap1[(size_t)((gp+3)*GS+i)*32]; }
            }
        }
    }

    // save h1 (lower) before the epilogue junks it, then finish last GRU2 step
    if (!last && lo) {
        hws[e0 * 64 + j] = hA;
        if (!dup) hws[e1 * 64 + j] = hB;
    }
    roundfn(make_float2(0.f, 0.f), make_float2(0.f, 0.f), false);
    if (!last) {
        if (!lo && j < L2) {
            hws[e0 * 64 + 32 + j] = hA;
            if (!dup) hws[e1 * 64 + 32 + j] = hB;
        }
        return;
    }

    // ---- tail: FC3+ReLU, FC4, log_softmax (per element; h2 = upper lanes)
    auto tail = [&](float hfin, float* op) {
        float s2[L2];
        #pragma unroll
        for (int k = 0; k < L2; ++k) s2[k] = rl(hfin, 32 + k);
        float a3 = 0.f;
        if (lane < L3) {
            a3 = b3[lane];
            #pragma unroll
            for (int k = 0; k < L2; ++k) a3 = fmaf(s2[k], w3[k * L3 + lane], a3);
            a3 = fmaxf(a3, 0.f);
        }
        float s3[L3];
        #pragma unroll
        for (int k = 0; k < L3; ++k) s3[k] = rl(a3, k);
        float a4 = 0.f;
        if (lane < NCLASS) {
            a4 = b4[lane];
            #pragma unroll
            for (int k = 0; k < L3; ++k) a4 = fmaf(s3[k], w4[k * NCLASS + lane], a4);
        }
        float s4[NCLASS];
        #pragma unroll
        for (int k = 0; k < NCLASS; ++k) s4[k] = rl(a4, k);
        float m = s4[0];
        #pragma unroll
        for (int k = 1; k < NCLASS; ++k) m = fmaxf(m, s4[k]);
        float ss = 0.f;
        #pragma unroll
        for (int k = 0; k < NCLASS; ++k)
            ss += __builtin_amdgcn_exp2f((s4[k] - m) * LOG2E);
        float lse = m + __builtin_amdgcn_logf(ss) * LN2;
        if (lane < NCLASS) op[lane] = s4[lane] - lse;
    };
    tail(hA, outg + e0 * NCLASS);
    tail(hB, outg + e1 * NCLASS);
}

extern "C" void kernel_launch(void* const* d_in, const int* in_sizes, int n_in,
                              void* d_out, int out_size, void* d_ws, size_t ws_size,
                              hipStream_t stream) {
    const float* x   = (const float*)d_in[0];
    const float* wz1 = (const float*)d_in[1];
    const float* bz1 = (const float*)d_in[2];
    const float* wh1 = (const float*)d_in[3];
    const float* bh1 = (const float*)d_in[4];
    const float* wz2 = (const float*)d_in[5];
    const float* bz2 = (const float*)d_in[6];
    const float* wh2 = (const float*)d_in[7];
    const float* bh2 = (const float*)d_in[8];
    const float* w3  = (const float*)d_in[9];
    const float* b3  = (const float*)d_in[10];
    const float* w4  = (const float*)d_in[11];
    const float* b4  = (const float*)d_in[12];
    float* out = (float*)d_out;

    const int Bsz = in_sizes[0] / (T * FBINS);          // 512

    float* hws = (float*)d_ws;
    float* axw = hws + (size_t)Bsz * 64;
    const size_t hbytes = (size_t)Bsz * 64 * sizeof(float);
    const size_t per_t  = (size_t)Bsz * 64 * sizeof(float);

    int segT = T;
    if (ws_size < hbytes + (size_t)T * per_t) {
        size_t avail = (ws_size > hbytes) ? ws_size - hbytes : 0;
        size_t s = avail / per_t;
        segT = (s > (size_t)T) ? T : (int)s;
        segT &= ~7;
        if (segT < 8) segT = 8;
    }

    const int nblk = (Bsz + 1) / 2;
    for (int t0 = 0; t0 < T; t0 += segT) {
        const int tc = (T - t0 < segT) ? (T - t0) : segT;
        dim3 g1(Bsz, (tc + TCH - 1) / TCH);
        xproj_kernel<<<g1, dim3(256), 0, stream>>>(x, wz1, bz1, wh1, bh1,
                                                   axw, t0, tc, segT);
        rec_kernel<<<dim3(nblk), dim3(64), 0, stream>>>(axw,
            wz1, wh1, wz2, bz2, wh2, bh2, w3, b3, w4, b4,
            hws, out, tc, segT, t0 == 0 ? 1 : 0, (t0 + tc >= T) ? 1 : 0, Bsz);
    }
}

// Round 8
// 362.987 us; speedup vs baseline: 1.9366x; 1.3695x over previous
//
#include <hip/hip_runtime.h>

// 2-layer GRU (T=1000 serial, B=512) + FC + log_softmax.
// Pass 1: ax[b,t] = (x_t @ W1x + b1) * LOG2E-scales -> d_ws, per-lane (z,g).
// Pass 2: one wave per batch element, skewed layers (lanes 0..31 = GRU1 unit j
//         @ step t, lanes 32..51 = GRU2 unit j @ step t-1). Each lane computes
//         BOTH of its unit's gates (z in .x, g in .y of packed v2f accums), so
//         the serial chain is: 52 readlane (dep only on h) -> 52 pk_fma
//         (4 indep chains) -> 9-op activation -> h. No shfl/bpermute/LDS on
//         the critical path. exp2 scale factors folded into weights/bias/ax.

typedef float v2f __attribute__((ext_vector_type(2)));

constexpr int FBINS  = 40;
constexpr int L1     = 32;
constexpr int L2     = 20;
constexpr int L3     = 16;
constexpr int NCLASS = 10;
constexpr int T      = 1000;
constexpr int KTOT   = L1 + L2;   // 52
constexpr float LOG2E = 1.4426950408889634f;
constexpr float LN2   = 0.6931471805599453f;

__device__ __forceinline__ float rl(float v, int l) {
    return __uint_as_float(__builtin_amdgcn_readlane(__float_as_uint(v), l));
}

// ---------------- pass 1: x-projection (pre-scaled by LOG2E / 2*LOG2E) ------
constexpr int TCH = 100;
__global__ __launch_bounds__(256) void xproj_kernel(
    const float* __restrict__ xg,
    const float* __restrict__ wz1, const float* __restrict__ bz1,
    const float* __restrict__ wh1, const float* __restrict__ bh1,
    float* __restrict__ ax, int t0, int tcnt, int segcap)
{
    __shared__ float xs[TCH * FBINS];
    const int tid = threadIdx.x, lane = tid & 63;
    const int b   = blockIdx.x;
    const int lt0 = blockIdx.y * TCH;
    const int cnt = min(TCH, tcnt - lt0);
    const float* src = xg + ((size_t)b * T + t0 + lt0) * FBINS;
    const int ndw = cnt * FBINS;
    for (int i = tid; i < ndw; i += 256) xs[i] = src[i];
    __syncthreads();

    const int j = lane & 31;
    const float* wp = (lane < 32) ? wz1 : wh1;   // lane<32: z-gate, else g-gate
    const float scale = (lane < 32) ? LOG2E : (2.0f * LOG2E);
    float w[FBINS];
    #pragma unroll
    for (int k = 0; k < FBINS; ++k) w[k] = wp[k * L1 + j] * scale;
    const float bias = ((lane < 32) ? bz1[j] : bh1[j]) * scale;
    const int slot = j * 2 + (lane >> 5);        // (z,g) interleaved pairs

    const int wv = tid >> 6;
    for (int lt = wv; lt < cnt; lt += 4) {
        const float* xp = xs + lt * FBINS;
        float a0 = bias, a1 = 0.f, a2 = 0.f, a3 = 0.f;
        #pragma unroll
        for (int k = 0; k < FBINS; k += 4) {
            a0 = fmaf(xp[k+0], w[k+0], a0);
            a1 = fmaf(xp[k+1], w[k+1], a1);
            a2 = fmaf(xp[k+2], w[k+2], a2);
            a3 = fmaf(xp[k+3], w[k+3], a3);
        }
        ax[((size_t)b * segcap + lt0 + lt) * 64 + slot] = (a0 + a1) + (a2 + a3);
    }
}

// ---------------- pass 2: skewed recurrence, both gates per lane ------------
constexpr int GS = 8;      // steps per prefetch group (double-buffered)
__global__ __launch_bounds__(64) void rec_kernel(
    const float* __restrict__ ax,
    const float* __restrict__ wz1, const float* __restrict__ wh1,
    const float* __restrict__ wz2, const float* __restrict__ bz2,
    const float* __restrict__ wh2, const float* __restrict__ bh2,
    const float* __restrict__ w3,  const float* __restrict__ b3,
    const float* __restrict__ w4,  const float* __restrict__ b4,
    float* __restrict__ hws, float* __restrict__ outg,
    int tcnt, int segcap, int first, int last)
{
    const int lane = threadIdx.x;
    const int b    = blockIdx.x;
    const int j    = lane & 31;
    const bool lo  = lane < 32;
    const int j2   = (j < L2) ? j : 0;           // clamp junk lanes 52..63

    // per-lane weight pairs {wZ[k], wG[k]} over K (pre-scaled).
    // lower lane j: GRU1 h-part rows (40..71), zero-padded for k>=32.
    // upper lane 32+j: GRU2 full rows 0..51.
    v2f wzg[KTOT];
    #pragma unroll
    for (int k = 0; k < L1; ++k) {
        wzg[k].x = (lo ? wz1[(FBINS + k) * L1 + j] : wz2[k * L2 + j2]) * LOG2E;
        wzg[k].y = (lo ? wh1[(FBINS + k) * L1 + j] : wh2[k * L2 + j2]) * (2.0f * LOG2E);
    }
    #pragma unroll
    for (int k = 0; k < L2; ++k) {
        wzg[L1 + k].x = lo ? 0.f : wz2[(L1 + k) * L2 + j2] * LOG2E;
        wzg[L1 + k].y = lo ? 0.f : wh2[(L1 + k) * L2 + j2] * (2.0f * LOG2E);
    }
    const float initZ = bz2[j2] * LOG2E;          // used by upper lanes only
    const float initG = bh2[j2] * (2.0f * LOG2E);

    const float up0 = first ? 0.f : hws[b * 64 + 32 + j2];   // h2 restore
    float h = lo ? (first ? 0.f : hws[b * 64 + j]) : up0;

    const float2* axp = (const float2*)ax + (size_t)b * segcap * 32 + j;

    auto step = [&](float2 axv) {
        // broadcast h -> 52 wave-uniform values (SGPRs), dep only on h
        float sh[KTOT];
        #pragma unroll
        for (int k = 0; k < KTOT; ++k) sh[k] = rl(h, k);
        // packed dot: z in .x, g in .y; 4 independent chains
        v2f a0 = lo ? (v2f){axv.x, axv.y} : (v2f){initZ, initG};
        v2f a1 = {0.f, 0.f}, a2 = {0.f, 0.f}, a3 = {0.f, 0.f};
        #pragma unroll
        for (int k = 0; k < KTOT; k += 4) {
            a0 = __builtin_elementwise_fma((v2f){sh[k+0], sh[k+0]}, wzg[k+0], a0);
            a1 = __builtin_elementwise_fma((v2f){sh[k+1], sh[k+1]}, wzg[k+1], a1);
            a2 = __builtin_elementwise_fma((v2f){sh[k+2], sh[k+2]}, wzg[k+2], a2);
            a3 = __builtin_elementwise_fma((v2f){sh[k+3], sh[k+3]}, wzg[k+3], a3);
        }
        v2f zg = (a0 + a1) + (a2 + a3);
        // z = sigmoid(zg.x/LOG2E) via exp2; tanh(g) = 2*rcp(1+exp2(-2g*LOG2E))-1
        float ez  = __builtin_amdgcn_exp2f(-zg.x);
        float s   = __builtin_amdgcn_rcpf(1.f + ez);
        float eg  = __builtin_amdgcn_exp2f(-zg.y);
        float r   = __builtin_amdgcn_rcpf(1.f + eg);
        float hp1 = 1.f + h;
        float d   = fmaf(2.f, r, -hp1);           // tanh(g) - h
        h = fmaf(s, d, h);                        // (1-z)h + z*tanh(g)
    };

    // ---- pipelined loop, GS-step groups, double-buffered register prefetch
    float2 bufA[GS], bufB[GS];
    const int ng = tcnt / GS;                    // tcnt multiple of 8
    #pragma unroll
    for (int i = 0; i < GS; ++i) bufA[i] = axp[(size_t)i * 32];
    if (1 < ng) {
        #pragma unroll
        for (int i = 0; i < GS; ++i) bufB[i] = axp[(size_t)(GS + i) * 32];
    }

    // group 0: round 0's upper output is junk (GRU2 @ t=-1); restore h2.
    step(bufA[0]);
    h = lo ? h : up0;
    #pragma unroll
    for (int i = 1; i < GS; ++i) step(bufA[i]);
    if (2 < ng) {
        #pragma unroll
        for (int i = 0; i < GS; ++i) bufA[i] = axp[(size_t)(2 * GS + i) * 32];
    }
    #pragma unroll 1
    for (int gp = 1; gp < ng; gp += 2) {
        #pragma unroll
        for (int i = 0; i < GS; ++i) step(bufB[i]);
        if (gp + 2 < ng) {
            #pragma unroll
            for (int i = 0; i < GS; ++i) bufB[i] = axp[(size_t)((gp + 2) * GS + i) * 32];
        }
        if (gp + 1 < ng) {
            #pragma unroll
            for (int i = 0; i < GS; ++i) step(bufA[i]);
            if (gp + 3 < ng) {
                #pragma unroll
                for (int i = 0; i < GS; ++i) bufA[i] = axp[(size_t)((gp + 3) * GS + i) * 32];
            }
        }
    }

    // save h1 (lower) before the epilogue junks it; then finish GRU2(tcnt-1)
    if (!last && lo) hws[b * 64 + j] = h;
    step(make_float2(0.f, 0.f));
    if (!last) {
        if (!lo && j < L2) hws[b * 64 + 32 + j] = h;
        return;
    }

    // ---- tail: FC3+ReLU, FC4, log_softmax (h2 = upper lanes of h) ----
    float s2[L2];
    #pragma unroll
    for (int k = 0; k < L2; ++k) s2[k] = rl(h, 32 + k);
    float a3 = 0.f;
    if (lane < L3) {
        a3 = b3[lane];
        #pragma unroll
        for (int k = 0; k < L2; ++k) a3 = fmaf(s2[k], w3[k * L3 + lane], a3);
        a3 = fmaxf(a3, 0.f);
    }
    float s3[L3];
    #pragma unroll
    for (int k = 0; k < L3; ++k) s3[k] = rl(a3, k);
    float a4 = 0.f;
    if (lane < NCLASS) {
        a4 = b4[lane];
        #pragma unroll
        for (int k = 0; k < L3; ++k) a4 = fmaf(s3[k], w4[k * NCLASS + lane], a4);
    }
    float s4[NCLASS];
    #pragma unroll
    for (int k = 0; k < NCLASS; ++k) s4[k] = rl(a4, k);
    float m = s4[0];
    #pragma unroll
    for (int k = 1; k < NCLASS; ++k) m = fmaxf(m, s4[k]);
    float ss = 0.f;
    #pragma unroll
    for (int k = 0; k < NCLASS; ++k)
        ss += __builtin_amdgcn_exp2f((s4[k] - m) * LOG2E);
    float lse = m + __builtin_amdgcn_logf(ss) * LN2;
    if (lane < NCLASS) outg[b * NCLASS + lane] = s4[lane] - lse;
}

extern "C" void kernel_launch(void* const* d_in, const int* in_sizes, int n_in,
                              void* d_out, int out_size, void* d_ws, size_t ws_size,
                              hipStream_t stream) {
    const float* x   = (const float*)d_in[0];
    const float* wz1 = (const float*)d_in[1];
    const float* bz1 = (const float*)d_in[2];
    const float* wh1 = (const float*)d_in[3];
    const float* bh1 = (const float*)d_in[4];
    const float* wz2 = (const float*)d_in[5];
    const float* bz2 = (const float*)d_in[6];
    const float* wh2 = (const float*)d_in[7];
    const float* bh2 = (const float*)d_in[8];
    const float* w3  = (const float*)d_in[9];
    const float* b3  = (const float*)d_in[10];
    const float* w4  = (const float*)d_in[11];
    const float* b4  = (const float*)d_in[12];
    float* out = (float*)d_out;

    const int Bsz = in_sizes[0] / (T * FBINS);          // 512

    float* hws = (float*)d_ws;                          // Bsz*64 floats h state
    float* axw = hws + (size_t)Bsz * 64;
    const size_t hbytes = (size_t)Bsz * 64 * sizeof(float);
    const size_t per_t  = (size_t)Bsz * 64 * sizeof(float);

    int segT = T;
    if (ws_size < hbytes + (size_t)T * per_t) {
        size_t avail = (ws_size > hbytes) ? ws_size - hbytes : 0;
        size_t s = avail / per_t;
        segT = (s > (size_t)T) ? T : (int)s;
        segT &= ~7;
        if (segT < 8) segT = 8;
    }

    for (int t0 = 0; t0 < T; t0 += segT) {
        const int tc = (T - t0 < segT) ? (T - t0) : segT;
        dim3 g1(Bsz, (tc + TCH - 1) / TCH);
        xproj_kernel<<<g1, dim3(256), 0, stream>>>(x, wz1, bz1, wh1, bh1,
                                                   axw, t0, tc, segT);
        rec_kernel<<<dim3(Bsz), dim3(64), 0, stream>>>(axw,
            wz1, wh1, wz2, bz2, wh2, bh2, w3, b3, w4, b4,
            hws, out, tc, segT, t0 == 0 ? 1 : 0, (t0 + tc >= T) ? 1 : 0);
    }
}